// Round 7
// baseline (1106.487 us; speedup 1.0000x reference)
//
#include <hip/hip_runtime.h>
#include <stdint.h>

// Problem constants (fixed by reference)
#define NB 2048           // batch N
#define NI 256            // input dim I
#define NJ 256            // out dim J
#define GK 300            // grid size K
#define SPLITK 32
#define II_PER_S (NI / SPLITK)   // 8 i-values per split-k slice
#define BM 128
#define CH 19             // 32-kk chunks per i: k=1..304, k>300 masked to zero
#define ROW4 75           // float4s per (d,j,i) coeff row (300 floats)
#define SINOFF4 ((unsigned)(NJ * NI * ROW4))   // +78.6MB in float4 units

#define P_BYTES  ((size_t)SPLITK * NB * NJ * 4)     // 64 MiB partial tiles

typedef __bf16 bf16x8 __attribute__((ext_vector_type(8)));
typedef __bf16 bf16x2 __attribute__((ext_vector_type(2)));
typedef float  f32x4  __attribute__((ext_vector_type(4)));

__device__ __forceinline__ void sincos2pi(float ang, float& c, float& s) {
  float r = ang * 0.15915494309189535f;   // 1/(2*pi)
  r = r - floorf(r);
  c = __builtin_amdgcn_cosf(r);
  s = __builtin_amdgcn_sinf(r);
}

__device__ __forceinline__ unsigned int pkbf(float c, float s) {
  bf16x2 p; p.x = (__bf16)c; p.y = (__bf16)s;
  return __builtin_bit_cast(unsigned int, p);
}

__device__ __forceinline__ void rot(float& c, float& s, float cr, float sr) {
  float nc = c * cr - s * sr;
  s = s * cr + c * sr;
  c = nc;
}

// ---------------------------------------------------------------------------
// Pass 1 (atomic fallback path only): out[n][j] = bias[j]
// ---------------------------------------------------------------------------
__global__ __launch_bounds__(256) void init_out(const float* __restrict__ bias,
                                                float* __restrict__ out) {
  const int tid = blockIdx.x * 256 + threadIdx.x;     // 131072 float4s
  float4 b = ((const float4*)bias)[tid & 63];
  ((float4*)out)[tid] = b;
}

// ---------------------------------------------------------------------------
// Fused GEMM: C[2048][256] += A * Bt over KK = 2*304*256 (k>300 zeroed).
// v6: convert_b ELIMINATED — B fragments are built in-register from the
// original fp32 coeffs [2][J][I][300]. Per lane per frag: cos float4 +
// sin float4 (16B-aligned, contiguous) -> 4x pkbf -> bf16 fragment, exactly
// the layout convert_b produced. Saves the 84MB ws round-trip and the whole
// convert dispatch (~150-200us of the 242us non-gemm residual).
//
// Pipeline per chunk: {cvt f->b | issue other-half loads | A-gen | 16 MFMAs}
// x2 halves; fp32 in-flight buffer f[8] (32 VGPR), bf16 half-buffer b[4].
// NO LDS, NO barriers. A-fragments via in-register rotation as before.
// Block 128m x 256n, 4 waves, wave tile 64x128. Grid 16mt x 32s = 512
// blocks, XCD-swizzled so each XCD's 4 slices stream coeffs from its L2.
// Chunk 18 (k=289..304): q==3 lanes (k>300) load-masked to zero.
// ---------------------------------------------------------------------------
template <int MODE>   // 0: atomicAdd into out; 1: store partial P[s]
__global__ __launch_bounds__(256, 2) void fkan_gemm(const float* __restrict__ x,
                                                    const float* __restrict__ coeffs,
                                                    float* __restrict__ dst) {
  const int bid  = blockIdx.x;
  const int virt = (bid & 7) * 64 + (bid >> 3);   // bijective: 512 = 8 XCD * 64
  const int mt = virt & 15;
  const int s  = virt >> 4;         // split-k slice (i range s*8 .. s*8+7)
  const int m0 = mt * BM;

  const int t    = (int)threadIdx.x;
  const int lane = t & 63;
  const int wave = t >> 6;
  const int wr = wave >> 1;         // m half (64 rows)
  const int wc = wave & 1;          // n half (128 cols)
  const int q  = lane >> 4;         // quad -> k sub-block
  const int ln = lane & 15;         // row (A) / col (B) within 16-tile

  const float4* __restrict__ cf4 = (const float4*)coeffs;

  f32x4 acc[4][8];
  #pragma unroll
  for (int mm = 0; mm < 4; mm++)
    #pragma unroll
    for (int nn = 0; nn < 8; nn++)
      acc[mm][nn] = (f32x4){0.f, 0.f, 0.f, 0.f};

  float stc[4], sts[4], c1a[4], s1a[4], cDa[4], sDa[4];
  float4 f[8];     // fp32 in-flight: [frag u][cos=0/sin=1] -> f[2u+d]
  uint4  b[4];     // bf16 current half fragments
  bf16x8 af[4];    // A fragments for current chunk

  #pragma unroll 1
  for (int ii = 0; ii < II_PER_S; ii++) {
    const int i = s * II_PER_S + ii;

    // Per-frag fp32 row index (float4 units): frag nn -> j = (wc*8+nn)*16+ln;
    // idx + c*4 is the cos float4 for k = 16c+4q+1..+4; sin at +SINOFF4.
    unsigned idx[8];
    #pragma unroll
    for (int nn = 0; nn < 8; nn++)
      idx[nn] = (unsigned)((((wc * 8 + nn) * 16 + ln) * NI + i)) * ROW4 + (unsigned)q;

    // Trig seeds. Lane's A rows: m0 + wr*64 + mm*16 + ln.
    #pragma unroll
    for (int mm = 0; mm < 4; mm++) {
      const float xv = x[(m0 + wr * 64 + mm * 16 + ln) * NI + i];
      sincos2pi(xv, c1a[mm], s1a[mm]);          // rotate-by-1 step
      sincos2pi(13.f * xv, cDa[mm], sDa[mm]);   // rotate-by-13 (chunk advance)
      sincos2pi(xv * (float)(q * 4 + 1), stc[mm], sts[mm]);  // state @ k=q*4+1
    }

    // Prologue: issue loads for (c=0, half0). Chunk 0 is never masked.
    #pragma unroll
    for (int u = 0; u < 4; u++) {
      const unsigned id = idx[u];
      f[2*u]   = cf4[id];
      f[2*u+1] = cf4[id + SINOFF4];
    }

    #pragma unroll 1
    for (int c = 0; c < CH; c++) {
      // ---- half 0 (frags nn = 0..3) ----
      // cvt f -> b (implicit wait on half0 loads)
      #pragma unroll
      for (int u = 0; u < 4; u++) {
        uint4 w;
        w.x = pkbf(f[2*u].x, f[2*u+1].x);
        w.y = pkbf(f[2*u].y, f[2*u+1].y);
        w.z = pkbf(f[2*u].z, f[2*u+1].z);
        w.w = pkbf(f[2*u].w, f[2*u+1].w);
        b[u] = w;
      }
      // issue (c, half1) loads; chunk CH-1 masks q==3 (k 301..304 -> 0)
      if (c < CH - 1) {
        #pragma unroll
        for (int u = 0; u < 4; u++) {
          const unsigned id = idx[4+u] + (unsigned)(c * 4);
          f[2*u]   = cf4[id];
          f[2*u+1] = cf4[id + SINOFF4];
        }
      } else {
        const float4 zz = {0.f, 0.f, 0.f, 0.f};
        #pragma unroll
        for (int u = 0; u < 4; u++) {
          const unsigned id = idx[4+u] + (unsigned)(c * 4);
          f[2*u]   = (q < 3) ? cf4[id] : zz;
          f[2*u+1] = (q < 3) ? cf4[id + SINOFF4] : zz;
        }
      }

      // A fragments for chunk c: [cos,sin] at k = 16c + 4q + {1,2,3,4}
      #pragma unroll
      for (int mm = 0; mm < 4; mm++) {
        float cc = stc[mm], ss = sts[mm];
        uint4 u;
        u.x = pkbf(cc, ss);
        rot(cc, ss, c1a[mm], s1a[mm]); u.y = pkbf(cc, ss);
        rot(cc, ss, c1a[mm], s1a[mm]); u.z = pkbf(cc, ss);
        rot(cc, ss, c1a[mm], s1a[mm]); u.w = pkbf(cc, ss);
        rot(cc, ss, cDa[mm], sDa[mm]); stc[mm] = cc; sts[mm] = ss;
        af[mm] = __builtin_bit_cast(bf16x8, u);
      }

      // MFMA half0
      #pragma unroll
      for (int u = 0; u < 4; u++) {
        const bf16x8 bfr = __builtin_bit_cast(bf16x8, b[u]);
        #pragma unroll
        for (int mm = 0; mm < 4; mm++)
          acc[mm][u] = __builtin_amdgcn_mfma_f32_16x16x32_bf16(
              af[mm], bfr, acc[mm][u], 0, 0, 0);
      }

      // ---- half 1 (frags nn = 4..7) ----
      #pragma unroll
      for (int u = 0; u < 4; u++) {
        uint4 w;
        w.x = pkbf(f[2*u].x, f[2*u+1].x);
        w.y = pkbf(f[2*u].y, f[2*u+1].y);
        w.z = pkbf(f[2*u].z, f[2*u+1].z);
        w.w = pkbf(f[2*u].w, f[2*u+1].w);
        b[u] = w;
      }
      // issue (c+1, half0) loads; mask if c+1 is the last chunk
      if (c + 1 < CH - 1) {
        #pragma unroll
        for (int u = 0; u < 4; u++) {
          const unsigned id = idx[u] + (unsigned)((c + 1) * 4);
          f[2*u]   = cf4[id];
          f[2*u+1] = cf4[id + SINOFF4];
        }
      } else if (c + 1 == CH - 1) {
        const float4 zz = {0.f, 0.f, 0.f, 0.f};
        #pragma unroll
        for (int u = 0; u < 4; u++) {
          const unsigned id = idx[u] + (unsigned)((c + 1) * 4);
          f[2*u]   = (q < 3) ? cf4[id] : zz;
          f[2*u+1] = (q < 3) ? cf4[id + SINOFF4] : zz;
        }
      }  // c+1 == CH: skip; next ii prologue refills

      // MFMA half1
      #pragma unroll
      for (int u = 0; u < 4; u++) {
        const bf16x8 bfr = __builtin_bit_cast(bf16x8, b[u]);
        #pragma unroll
        for (int mm = 0; mm < 4; mm++)
          acc[mm][4+u] = __builtin_amdgcn_mfma_f32_16x16x32_bf16(
              af[mm], bfr, acc[mm][4+u], 0, 0, 0);
      }
    }
  }

  // ---- Epilogue (C/D layout: col=lane&15, row=q*4+r) ----
  const int r0 = m0 + wr * 64 + q * 4;
  const int c0 = wc * 128 + ln;
  if (MODE == 0) {
    #pragma unroll
    for (int mm = 0; mm < 4; mm++)
      #pragma unroll
      for (int nn = 0; nn < 8; nn++)
        #pragma unroll
        for (int r = 0; r < 4; r++)
          atomicAdd(&dst[(r0 + mm * 16 + r) * NJ + c0 + nn * 16], acc[mm][nn][r]);
  } else {
    float* p = dst + (size_t)s * NB * NJ;
    #pragma unroll
    for (int mm = 0; mm < 4; mm++)
      #pragma unroll
      for (int nn = 0; nn < 8; nn++)
        #pragma unroll
        for (int r = 0; r < 4; r++)
          p[(r0 + mm * 16 + r) * NJ + c0 + nn * 16] = acc[mm][nn][r];
  }
}

// ---------------------------------------------------------------------------
// Pass 2 (partial path): out[m][j] = bias[j] + sum_s P[s][m][j]
// 64MB coalesced read, 2MB write.
// ---------------------------------------------------------------------------
__global__ __launch_bounds__(256) void reduce_out(const float* __restrict__ P,
                                                  const float* __restrict__ bias,
                                                  float* __restrict__ out) {
  const int m = blockIdx.x;            // 0..2047
  const int j = (int)threadIdx.x;      // 0..255
  const size_t base = (size_t)m * NJ + j;
  float acc = bias[j];
  #pragma unroll
  for (int s = 0; s < SPLITK; s++)
    acc += P[(size_t)s * NB * NJ + base];
  out[base] = acc;
}

// ---------------------------------------------------------------------------
extern "C" void kernel_launch(void* const* d_in, const int* in_sizes, int n_in,
                              void* d_out, int out_size, void* d_ws, size_t ws_size,
                              hipStream_t stream) {
  const float* x      = (const float*)d_in[0];   // [2048, 256]
  const float* coeffs = (const float*)d_in[1];   // [2, 256, 256, 300]
  const float* bias   = (const float*)d_in[2];   // [1, 256]
  float* out = (float*)d_out;                    // [2048, 256] fp32

  if (ws_size >= P_BYTES) {
    // Partial-tile path: streaming stores + reduction (no fabric RMW tail)
    float* P = (float*)d_ws;
    fkan_gemm<1><<<dim3(16 * SPLITK), dim3(256), 0, stream>>>(x, coeffs, P);
    reduce_out<<<dim3(NB), dim3(256), 0, stream>>>(P, bias, out);
  } else {
    // Fallback: split-K atomics directly into out
    init_out<<<dim3(NB * NJ / 4 / 256), dim3(256), 0, stream>>>(bias, out);
    fkan_gemm<0><<<dim3(16 * SPLITK), dim3(256), 0, stream>>>(x, coeffs, out);
  }
}

// Round 8
// 865.097 us; speedup vs baseline: 1.2790x; 1.2790x over previous
//
#include <hip/hip_runtime.h>
#include <stdint.h>

// Problem constants (fixed by reference)
#define NB 2048           // batch N
#define NI 256            // input dim I
#define NJ 256            // out dim J
#define GK 300            // grid size K
#define SPLITK 32
#define II_PER_S (NI / SPLITK)   // 8 i-values per split-k slice
#define BM 128
#define CH 19             // 32-kk chunks per i: k=1..304, k>300 masked to zero
#define ROW4 75           // float4s per (d,j,i) coeff row (300 floats)
#define NSTR 307200u      // 16*NI*ROW4: float4 stride between fragment j-groups
#define SINOFF4 4915200u  // NJ*NI*ROW4: cos block -> sin block offset (float4)

#define P_BYTES  ((size_t)SPLITK * NB * NJ * 4)     // 64 MiB partial tiles

typedef __bf16 bf16x8 __attribute__((ext_vector_type(8)));
typedef __bf16 bf16x2 __attribute__((ext_vector_type(2)));
typedef float  f32x4  __attribute__((ext_vector_type(4)));

__device__ __forceinline__ void sincos2pi(float ang, float& c, float& s) {
  float r = ang * 0.15915494309189535f;   // 1/(2*pi)
  r = r - floorf(r);
  c = __builtin_amdgcn_cosf(r);
  s = __builtin_amdgcn_sinf(r);
}

__device__ __forceinline__ unsigned int pkbf(float c, float s) {
  bf16x2 p; p.x = (__bf16)c; p.y = (__bf16)s;
  return __builtin_bit_cast(unsigned int, p);
}

__device__ __forceinline__ void rot(float& c, float& s, float cr, float sr) {
  float nc = c * cr - s * sr;
  s = s * cr + c * sr;
  c = nc;
}

// ---------------------------------------------------------------------------
// Pass 1 (atomic fallback path only): out[n][j] = bias[j]
// ---------------------------------------------------------------------------
__global__ __launch_bounds__(256) void init_out(const float* __restrict__ bias,
                                                float* __restrict__ out) {
  const int tid = blockIdx.x * 256 + threadIdx.x;     // 131072 float4s
  float4 b = ((const float4*)bias)[tid & 63];
  ((float4*)out)[tid] = b;
}

// ---------------------------------------------------------------------------
// Fused GEMM: C[2048][256] += A * Bt over KK = 2*304*256 (k>300 zeroed).
// B fragments built in-register from fp32 coeffs [2][J][I][300] (v6 math,
// r7-verified correct). v7 fixes v6's register spill (VGPR demand ~8 over
// the 128-VGPR/128-AGPR unified budget -> 758MB scratch traffic, 979us):
//  - idx[8] array -> single base0 VGPR; frag offsets are compile-time
//    multiples of NSTR; chunk advance via wave-uniform pc/ps (SGPR).
//  - b[4] buffer -> one fragment: cvt fused immediately before each MFMA
//    quad; half1 loads trickle-issued into the g-regs freed by each cvt
//    (staging peak unchanged at 8 float4, prefetch distance ~3 quads).
// Est. ~95 VGPR + 128 AGPR = ~223 <= 256 (v5 ran spill-free at 240).
// Block 128m x 256n, 4 waves, wave tile 64x128. Grid 16mt x 32s = 512
// blocks, XCD-swizzled (slice's coeffs stream pinned to one XCD L2).
// Chunk CH-1 (k=289..304): q==3 lanes (k>300) masked to zero.
// ---------------------------------------------------------------------------
template <int MODE>   // 0: atomicAdd into out; 1: store partial P[s]
__global__ __launch_bounds__(256, 2) void fkan_gemm(const float* __restrict__ x,
                                                    const float* __restrict__ coeffs,
                                                    float* __restrict__ dst) {
  const int bid  = blockIdx.x;
  const int virt = (bid & 7) * 64 + (bid >> 3);   // bijective: 512 = 8 XCD * 64
  const int mt = virt & 15;
  const int s  = virt >> 4;         // split-k slice (i range s*8 .. s*8+7)
  const int m0 = mt * BM;

  const int t    = (int)threadIdx.x;
  const int lane = t & 63;
  const int wave = t >> 6;
  const int wr = wave >> 1;         // m half (64 rows)
  const int wc = wave & 1;          // n half (128 cols)
  const int q  = lane >> 4;         // quad -> k sub-block
  const int ln = lane & 15;         // row (A) / col (B) within 16-tile

  const float4* __restrict__ cf4 = (const float4*)coeffs;

  f32x4 acc[4][8];
  #pragma unroll
  for (int mm = 0; mm < 4; mm++)
    #pragma unroll
    for (int nn = 0; nn < 8; nn++)
      acc[mm][nn] = (f32x4){0.f, 0.f, 0.f, 0.f};

  float stc[4], sts[4], c1a[4], s1a[4], cDa[4], sDa[4];
  float4 g0, g1, g2, g3, g4, g5, g6, g7;   // fp32 staging: 4 frags x (cos,sin)
  bf16x8 af[4];                            // A fragments for current chunk
  const float4 zz = {0.f, 0.f, 0.f, 0.f};

// cvt one fragment (cos float4 + sin float4 -> bf16x8) then its 4 MFMAs
#define CVTMF(U_, GC_, GS_) {                                              \
    uint4 w_;                                                              \
    w_.x = pkbf((GC_).x, (GS_).x); w_.y = pkbf((GC_).y, (GS_).y);          \
    w_.z = pkbf((GC_).z, (GS_).z); w_.w = pkbf((GC_).w, (GS_).w);          \
    const bf16x8 bu_ = __builtin_bit_cast(bf16x8, w_);                     \
    _Pragma("unroll")                                                      \
    for (int mm_ = 0; mm_ < 4; mm_++)                                      \
      acc[mm_][U_] = __builtin_amdgcn_mfma_f32_16x16x32_bf16(              \
          af[mm_], bu_, acc[mm_][U_], 0, 0, 0);                            \
  }

  #pragma unroll 1
  for (int ii = 0; ii < II_PER_S; ii++) {
    const int i = s * II_PER_S + ii;
    // frag nn cos float4 (chunk c): pc[base0 + nn*NSTR] after c pointer steps
    const unsigned base0 = (unsigned)((wc * 128 + ln) * NI + i) * ROW4 + (unsigned)q;
    const float4* __restrict__ pc = cf4;            // cos base, +4/chunk
    const float4* __restrict__ ps = cf4 + SINOFF4;  // sin base, +4/chunk

    // Trig seeds. Lane's A rows: m0 + wr*64 + mm*16 + ln.
    #pragma unroll
    for (int mm = 0; mm < 4; mm++) {
      const float xv = x[(m0 + wr * 64 + mm * 16 + ln) * NI + i];
      sincos2pi(xv, c1a[mm], s1a[mm]);          // rotate-by-1 step
      sincos2pi(13.f * xv, cDa[mm], sDa[mm]);   // rotate-by-13 (chunk advance)
      sincos2pi(xv * (float)(q * 4 + 1), stc[mm], sts[mm]);  // state @ k=q*4+1
    }

    // Prologue: chunk 0, half0 (frags 0..3); never masked.
    g0 = pc[base0];             g1 = ps[base0];
    g2 = pc[base0 + NSTR];      g3 = ps[base0 + NSTR];
    g4 = pc[base0 + 2*NSTR];    g5 = ps[base0 + 2*NSTR];
    g6 = pc[base0 + 3*NSTR];    g7 = ps[base0 + 3*NSTR];

    #pragma unroll 1
    for (int c = 0; c < CH; c++) {
      // A fragments for chunk c: [cos,sin] at k = 16c + 4q + {1,2,3,4}
      #pragma unroll
      for (int mm = 0; mm < 4; mm++) {
        float cc = stc[mm], ss = sts[mm];
        uint4 u;
        u.x = pkbf(cc, ss);
        rot(cc, ss, c1a[mm], s1a[mm]); u.y = pkbf(cc, ss);
        rot(cc, ss, c1a[mm], s1a[mm]); u.z = pkbf(cc, ss);
        rot(cc, ss, c1a[mm], s1a[mm]); u.w = pkbf(cc, ss);
        rot(cc, ss, cDa[mm], sDa[mm]); stc[mm] = cc; sts[mm] = ss;
        af[mm] = __builtin_bit_cast(bf16x8, u);
      }

      // ---- half0: frags 0..3; trickle-issue half1 (chunk c, frags 4..7)
      CVTMF(0, g0, g1);
      if (c < CH-1) { g0 = pc[base0 + 4*NSTR]; g1 = ps[base0 + 4*NSTR]; }
      else { g0 = (q < 3) ? pc[base0 + 4*NSTR] : zz;
             g1 = (q < 3) ? ps[base0 + 4*NSTR] : zz; }
      CVTMF(1, g2, g3);
      if (c < CH-1) { g2 = pc[base0 + 5*NSTR]; g3 = ps[base0 + 5*NSTR]; }
      else { g2 = (q < 3) ? pc[base0 + 5*NSTR] : zz;
             g3 = (q < 3) ? ps[base0 + 5*NSTR] : zz; }
      CVTMF(2, g4, g5);
      if (c < CH-1) { g4 = pc[base0 + 6*NSTR]; g5 = ps[base0 + 6*NSTR]; }
      else { g4 = (q < 3) ? pc[base0 + 6*NSTR] : zz;
             g5 = (q < 3) ? ps[base0 + 6*NSTR] : zz; }
      CVTMF(3, g6, g7);
      if (c < CH-1) { g6 = pc[base0 + 7*NSTR]; g7 = ps[base0 + 7*NSTR]; }
      else { g6 = (q < 3) ? pc[base0 + 7*NSTR] : zz;
             g7 = (q < 3) ? ps[base0 + 7*NSTR] : zz; }

      // ---- half1: frags 4..7; trickle-issue (chunk c+1, frags 0..3), +4 = next chunk
      CVTMF(4, g0, g1);
      if (c+1 < CH-1) { g0 = pc[base0 + 4]; g1 = ps[base0 + 4]; }
      else if (c+1 == CH-1) { g0 = (q < 3) ? pc[base0 + 4] : zz;
                              g1 = (q < 3) ? ps[base0 + 4] : zz; }
      CVTMF(5, g2, g3);
      if (c+1 < CH-1) { g2 = pc[base0 + NSTR + 4]; g3 = ps[base0 + NSTR + 4]; }
      else if (c+1 == CH-1) { g2 = (q < 3) ? pc[base0 + NSTR + 4] : zz;
                              g3 = (q < 3) ? ps[base0 + NSTR + 4] : zz; }
      CVTMF(6, g4, g5);
      if (c+1 < CH-1) { g4 = pc[base0 + 2*NSTR + 4]; g5 = ps[base0 + 2*NSTR + 4]; }
      else if (c+1 == CH-1) { g4 = (q < 3) ? pc[base0 + 2*NSTR + 4] : zz;
                              g5 = (q < 3) ? ps[base0 + 2*NSTR + 4] : zz; }
      CVTMF(7, g6, g7);
      if (c+1 < CH-1) { g6 = pc[base0 + 3*NSTR + 4]; g7 = ps[base0 + 3*NSTR + 4]; }
      else if (c+1 == CH-1) { g6 = (q < 3) ? pc[base0 + 3*NSTR + 4] : zz;
                              g7 = (q < 3) ? ps[base0 + 3*NSTR + 4] : zz; }
      // c+1 == CH: no issue; next ii's prologue refills.

      pc += 4; ps += 4;
    }
  }
#undef CVTMF

  // ---- Epilogue (C/D layout: col=lane&15, row=q*4+r) ----
  const int r0 = m0 + wr * 64 + q * 4;
  const int c0 = wc * 128 + ln;
  if (MODE == 0) {
    #pragma unroll
    for (int mm = 0; mm < 4; mm++)
      #pragma unroll
      for (int nn = 0; nn < 8; nn++)
        #pragma unroll
        for (int r = 0; r < 4; r++)
          atomicAdd(&dst[(r0 + mm * 16 + r) * NJ + c0 + nn * 16], acc[mm][nn][r]);
  } else {
    float* p = dst + (size_t)s * NB * NJ;
    #pragma unroll
    for (int mm = 0; mm < 4; mm++)
      #pragma unroll
      for (int nn = 0; nn < 8; nn++)
        #pragma unroll
        for (int r = 0; r < 4; r++)
          p[(r0 + mm * 16 + r) * NJ + c0 + nn * 16] = acc[mm][nn][r];
  }
}

// ---------------------------------------------------------------------------
// Pass 2 (partial path): out[m][j] = bias[j] + sum_s P[s][m][j]
// 64MB coalesced read, 2MB write.
// ---------------------------------------------------------------------------
__global__ __launch_bounds__(256) void reduce_out(const float* __restrict__ P,
                                                  const float* __restrict__ bias,
                                                  float* __restrict__ out) {
  const int m = blockIdx.x;            // 0..2047
  const int j = (int)threadIdx.x;      // 0..255
  const size_t base = (size_t)m * NJ + j;
  float acc = bias[j];
  #pragma unroll
  for (int s = 0; s < SPLITK; s++)
    acc += P[(size_t)s * NB * NJ + base];
  out[base] = acc;
}

// ---------------------------------------------------------------------------
extern "C" void kernel_launch(void* const* d_in, const int* in_sizes, int n_in,
                              void* d_out, int out_size, void* d_ws, size_t ws_size,
                              hipStream_t stream) {
  const float* x      = (const float*)d_in[0];   // [2048, 256]
  const float* coeffs = (const float*)d_in[1];   // [2, 256, 256, 300]
  const float* bias   = (const float*)d_in[2];   // [1, 256]
  float* out = (float*)d_out;                    // [2048, 256] fp32

  if (ws_size >= P_BYTES) {
    // Partial-tile path: streaming stores + reduction (no fabric RMW tail)
    float* P = (float*)d_ws;
    fkan_gemm<1><<<dim3(16 * SPLITK), dim3(256), 0, stream>>>(x, coeffs, P);
    reduce_out<<<dim3(NB), dim3(256), 0, stream>>>(P, bias, out);
  } else {
    // Fallback: split-K atomics directly into out
    init_out<<<dim3(NB * NJ / 4 / 256), dim3(256), 0, stream>>>(bias, out);
    fkan_gemm<0><<<dim3(16 * SPLITK), dim3(256), 0, stream>>>(x, coeffs, out);
  }
}